// Round 6
// baseline (8053.683 us; speedup 1.0000x reference)
//
#include <hip/hip_runtime.h>
#include <math.h>

#define SLEN 64
#define BATCH 256
#define VIND 128
#define VOUTD 128
#define UDIM 1024
#define EDIM 512
#define TDEC 25
#define GXW 1536
#define U3 3072

typedef __attribute__((ext_vector_type(8))) short short8;
typedef __attribute__((ext_vector_type(4))) float f32x4;

__device__ __forceinline__ float sigm(float x) { return 1.f / (1.f + expf(-x)); }

__device__ __forceinline__ short f2bf(float f) {
    unsigned u = __float_as_uint(f);
    u += 0x7FFF + ((u >> 16) & 1);
    return (short)(u >> 16);
}
__device__ __forceinline__ float bf2f(short h) {
    return __uint_as_float(((unsigned)(unsigned short)h) << 16);
}

// fragment-major packed layout for operand X[R][K]:
// chunk(r,k) holds X[r][k..k+8); lane = (r&15) + 16*((k>>3)&3)
__device__ __forceinline__ size_t pkChunk(int r, int k, int K) {
    return ((size_t)(r >> 4) * (K >> 5) + (k >> 5)) * 64 + ((r & 15) + 16 * ((k >> 3) & 3));
}

union S8 { short s[8]; short8 v; };

__device__ __forceinline__ void writeSplit8(short* Hi, short* Lo, size_t chunk,
                                            const float* vals) {
    S8 h, l;
#pragma unroll
    for (int j = 0; j < 8; j++) {
        short hb = f2bf(vals[j]);
        h.s[j] = hb;
        l.s[j] = f2bf(vals[j] - bf2f(hb));
    }
    ((short8*)Hi)[chunk] = h.v;
    ((short8*)Lo)[chunk] = l.v;
}

// ---------------------------------------------------------------------------
__global__ void init_kernel(float* __restrict__ h0, short* __restrict__ hpHi,
                            short* __restrict__ hpLo, float* __restrict__ out0,
                            int* __restrict__ idx) {
    int i = blockIdx.x * 256 + threadIdx.x;
    if (i < BATCH * UDIM) { h0[i] = 0.f; hpHi[i] = 0; hpLo[i] = 0; }
    if (i < BATCH * VOUTD) out0[i] = ((i & (VOUTD - 1)) == 0) ? 1.f : 0.f;
    if (i < BATCH) idx[i] = 0;
}

// ---------------------------------------------------------------------------
// pack src rows [rowOff, rowOff+R) of an [*, K] fp32 matrix into split planes
__global__ void pack_split2(const float* __restrict__ src, int rowOff, int K,
                            short* __restrict__ Hi, short* __restrict__ Lo,
                            int nChunks) {
    int gid = blockIdx.x * 256 + threadIdx.x;
    if (gid >= nChunks) return;
    int cpr = K >> 3;
    int r = gid / cpr, k0 = (gid - r * cpr) * 8;
    const float* s = src + (size_t)(rowOff + r) * K + k0;
    float v[8];
#pragma unroll
    for (int j = 0; j < 8; j++) v[j] = s[j];
    writeSplit8(Hi, Lo, pkChunk(r, k0, K), v);
}

// pack rows of [A | B] concatenated along K (KA multiple of 8)
__global__ void pack_cat(const float* __restrict__ sA, int KA, int offA,
                         const float* __restrict__ sB, int KB, int offB,
                         short* __restrict__ Hi, short* __restrict__ Lo,
                         int nChunks) {
    int gid = blockIdx.x * 256 + threadIdx.x;
    if (gid >= nChunks) return;
    int K = KA + KB;
    int cpr = K >> 3;
    int r = gid / cpr, k0 = (gid - r * cpr) * 8;
    float v[8];
    if (k0 < KA) {
        const float* s = sA + (size_t)(offA + r) * KA + k0;
#pragma unroll
        for (int j = 0; j < 8; j++) v[j] = s[j];
    } else {
        const float* s = sB + (size_t)(offB + r) * KB + (k0 - KA);
#pragma unroll
        for (int j = 0; j < 8; j++) v[j] = s[j];
    }
    writeSplit8(Hi, Lo, pkChunk(r, k0, K), v);
}

// ---------------------------------------------------------------------------
// Split-bf16 3-pass MFMA GEMM: C[M,N] = A @ W^T (+bias), fp32 out.
// ---------------------------------------------------------------------------
__global__ __launch_bounds__(256) void gemm_sp3(
    const short8* __restrict__ Ahi, const short8* __restrict__ Alo,
    const short8* __restrict__ Whi, const short8* __restrict__ Wlo,
    const float* __restrict__ bias, float* __restrict__ C,
    int KT, int N) {
    int tid = threadIdx.x, lane = tid & 63, wave = tid >> 6;
    int m16 = blockIdx.y * 4 + (wave & 1) * 2;
    int n16 = blockIdx.x * 4 + (wave >> 1) * 2;
    const short8* a0h = Ahi + (size_t)m16 * KT * 64 + lane;
    const short8* a1h = a0h + (size_t)KT * 64;
    const short8* a0l = Alo + (size_t)m16 * KT * 64 + lane;
    const short8* a1l = a0l + (size_t)KT * 64;
    const short8* w0h = Whi + (size_t)n16 * KT * 64 + lane;
    const short8* w1h = w0h + (size_t)KT * 64;
    const short8* w0l = Wlo + (size_t)n16 * KT * 64 + lane;
    const short8* w1l = w0l + (size_t)KT * 64;
    f32x4 acc00 = {0,0,0,0}, acc01 = {0,0,0,0}, acc10 = {0,0,0,0}, acc11 = {0,0,0,0};

    for (int kt = 0; kt < KT; kt++) {
        size_t o = (size_t)kt * 64;
        short8 A0H = a0h[o], A1H = a1h[o], A0L = a0l[o], A1L = a1l[o];
        short8 W0H = w0h[o], W1H = w1h[o], W0L = w0l[o], W1L = w1l[o];
        acc00 = __builtin_amdgcn_mfma_f32_16x16x32_bf16(A0H, W0H, acc00, 0, 0, 0);
        acc01 = __builtin_amdgcn_mfma_f32_16x16x32_bf16(A0H, W1H, acc01, 0, 0, 0);
        acc10 = __builtin_amdgcn_mfma_f32_16x16x32_bf16(A1H, W0H, acc10, 0, 0, 0);
        acc11 = __builtin_amdgcn_mfma_f32_16x16x32_bf16(A1H, W1H, acc11, 0, 0, 0);
        acc00 = __builtin_amdgcn_mfma_f32_16x16x32_bf16(A0H, W0L, acc00, 0, 0, 0);
        acc01 = __builtin_amdgcn_mfma_f32_16x16x32_bf16(A0H, W1L, acc01, 0, 0, 0);
        acc10 = __builtin_amdgcn_mfma_f32_16x16x32_bf16(A1H, W0L, acc10, 0, 0, 0);
        acc11 = __builtin_amdgcn_mfma_f32_16x16x32_bf16(A1H, W1L, acc11, 0, 0, 0);
        acc00 = __builtin_amdgcn_mfma_f32_16x16x32_bf16(A0L, W0H, acc00, 0, 0, 0);
        acc01 = __builtin_amdgcn_mfma_f32_16x16x32_bf16(A0L, W1H, acc01, 0, 0, 0);
        acc10 = __builtin_amdgcn_mfma_f32_16x16x32_bf16(A1L, W0H, acc10, 0, 0, 0);
        acc11 = __builtin_amdgcn_mfma_f32_16x16x32_bf16(A1L, W1H, acc11, 0, 0, 0);
    }
    int rsub = (lane >> 4) * 4, cn = lane & 15;
    float b0 = bias ? bias[(n16 + 0) * 16 + cn] : 0.f;
    float b1 = bias ? bias[(n16 + 1) * 16 + cn] : 0.f;
    int row0 = (m16 + 0) * 16 + rsub;
    int row1 = (m16 + 1) * 16 + rsub;
    int col0 = (n16 + 0) * 16 + cn;
    int col1 = (n16 + 1) * 16 + cn;
#pragma unroll
    for (int r = 0; r < 4; r++) {
        C[(size_t)(row0 + r) * N + col0] = acc00[r] + b0;
        C[(size_t)(row0 + r) * N + col1] = acc01[r] + b1;
        C[(size_t)(row1 + r) * N + col0] = acc10[r] + b0;
        C[(size_t)(row1 + r) * N + col1] = acc11[r] + b1;
    }
}

// ---------------------------------------------------------------------------
// Fully-fused GRU step: one kernel computes all gate GEMMs + nonlinearity.
// A = [h (K=1024, packed hi/lo) | xg (K=32*KTih, packed hi/lo)]
// Weights (packed, fragment-major): Wr,Wz over full K; Wnh over h-part only;
// Wni over xg-part only (n-gate ih/hh kept separate per GRU semantics).
// Block = 64 batch rows x (16 u's x 4 gate planes). Grid (64, 4) = 256 blocks.
// Epilogue exchanges planes via LDS, applies gates, writes h fp32 + packed
// (+ encoder enc_out packed).
// ---------------------------------------------------------------------------
__global__ __launch_bounds__(256) void gru_fused(
    const short8* __restrict__ hxHi, const short8* __restrict__ hxLo,
    const short8* __restrict__ xgHi, const short8* __restrict__ xgLo,
    const short8* __restrict__ WrHi, const short8* __restrict__ WrLo,
    const short8* __restrict__ WzHi, const short8* __restrict__ WzLo,
    const short8* __restrict__ WnhHi, const short8* __restrict__ WnhLo,
    const short8* __restrict__ WniHi, const short8* __restrict__ WniLo,
    const float* __restrict__ bih, const float* __restrict__ bhh,
    const float* __restrict__ hinF, float* __restrict__ houtF,
    short* __restrict__ hoHi, short* __restrict__ hoLo,
    short* __restrict__ eaHi, short* __restrict__ eaLo,
    const int* __restrict__ x_len, int t, int KTih) {
    __shared__ float sC[4][64][17];
    int tid = threadIdx.x, lane = tid & 63, wave = tid >> 6;
    int mloc = wave & 1, nrole = wave >> 1;
    int g = blockIdx.x;                 // u-group (16 u's)
    int m16 = blockIdx.y * 4 + mloc * 2;
    int KTfull = 32 + KTih;

    const short8* a0h = hxHi + (size_t)m16 * 32 * 64 + lane;
    const short8* a1h = a0h + 32 * 64;
    const short8* a0l = hxLo + (size_t)m16 * 32 * 64 + lane;
    const short8* a1l = a0l + 32 * 64;
    const short8* b0h = xgHi + (size_t)m16 * KTih * 64 + lane;
    const short8* b1h = b0h + (size_t)KTih * 64;
    const short8* b0l = xgLo + (size_t)m16 * KTih * 64 + lane;
    const short8* b1l = b0l + (size_t)KTih * 64;

    f32x4 accA0 = {0,0,0,0}, accA1 = {0,0,0,0}, accB0 = {0,0,0,0}, accB1 = {0,0,0,0};

    if (nrole == 0) {
        // planes r,z over full K
        const short8* wrh = WrHi + (size_t)g * KTfull * 64 + lane;
        const short8* wrl = WrLo + (size_t)g * KTfull * 64 + lane;
        const short8* wzh = WzHi + (size_t)g * KTfull * 64 + lane;
        const short8* wzl = WzLo + (size_t)g * KTfull * 64 + lane;
        for (int kt = 0; kt < 32; kt++) {
            size_t o = (size_t)kt * 64;
            short8 A0H = a0h[o], A1H = a1h[o], A0L = a0l[o], A1L = a1l[o];
            short8 RH = wrh[o], RL = wrl[o], ZH = wzh[o], ZL = wzl[o];
            accA0 = __builtin_amdgcn_mfma_f32_16x16x32_bf16(A0H, RH, accA0, 0, 0, 0);
            accA1 = __builtin_amdgcn_mfma_f32_16x16x32_bf16(A1H, RH, accA1, 0, 0, 0);
            accB0 = __builtin_amdgcn_mfma_f32_16x16x32_bf16(A0H, ZH, accB0, 0, 0, 0);
            accB1 = __builtin_amdgcn_mfma_f32_16x16x32_bf16(A1H, ZH, accB1, 0, 0, 0);
            accA0 = __builtin_amdgcn_mfma_f32_16x16x32_bf16(A0H, RL, accA0, 0, 0, 0);
            accA1 = __builtin_amdgcn_mfma_f32_16x16x32_bf16(A1H, RL, accA1, 0, 0, 0);
            accB0 = __builtin_amdgcn_mfma_f32_16x16x32_bf16(A0H, ZL, accB0, 0, 0, 0);
            accB1 = __builtin_amdgcn_mfma_f32_16x16x32_bf16(A1H, ZL, accB1, 0, 0, 0);
            accA0 = __builtin_amdgcn_mfma_f32_16x16x32_bf16(A0L, RH, accA0, 0, 0, 0);
            accA1 = __builtin_amdgcn_mfma_f32_16x16x32_bf16(A1L, RH, accA1, 0, 0, 0);
            accB0 = __builtin_amdgcn_mfma_f32_16x16x32_bf16(A0L, ZH, accB0, 0, 0, 0);
            accB1 = __builtin_amdgcn_mfma_f32_16x16x32_bf16(A1L, ZH, accB1, 0, 0, 0);
        }
        for (int kt = 0; kt < KTih; kt++) {
            size_t o = (size_t)kt * 64;
            size_t ow = (size_t)(32 + kt) * 64;
            short8 A0H = b0h[o], A1H = b1h[o], A0L = b0l[o], A1L = b1l[o];
            short8 RH = wrh[ow], RL = wrl[ow], ZH = wzh[ow], ZL = wzl[ow];
            accA0 = __builtin_amdgcn_mfma_f32_16x16x32_bf16(A0H, RH, accA0, 0, 0, 0);
            accA1 = __builtin_amdgcn_mfma_f32_16x16x32_bf16(A1H, RH, accA1, 0, 0, 0);
            accB0 = __builtin_amdgcn_mfma_f32_16x16x32_bf16(A0H, ZH, accB0, 0, 0, 0);
            accB1 = __builtin_amdgcn_mfma_f32_16x16x32_bf16(A1H, ZH, accB1, 0, 0, 0);
            accA0 = __builtin_amdgcn_mfma_f32_16x16x32_bf16(A0H, RL, accA0, 0, 0, 0);
            accA1 = __builtin_amdgcn_mfma_f32_16x16x32_bf16(A1H, RL, accA1, 0, 0, 0);
            accB0 = __builtin_amdgcn_mfma_f32_16x16x32_bf16(A0H, ZL, accB0, 0, 0, 0);
            accB1 = __builtin_amdgcn_mfma_f32_16x16x32_bf16(A1H, ZL, accB1, 0, 0, 0);
            accA0 = __builtin_amdgcn_mfma_f32_16x16x32_bf16(A0L, RH, accA0, 0, 0, 0);
            accA1 = __builtin_amdgcn_mfma_f32_16x16x32_bf16(A1L, RH, accA1, 0, 0, 0);
            accB0 = __builtin_amdgcn_mfma_f32_16x16x32_bf16(A0L, ZH, accB0, 0, 0, 0);
            accB1 = __builtin_amdgcn_mfma_f32_16x16x32_bf16(A1L, ZH, accB1, 0, 0, 0);
        }
    } else {
        // plane n_hh over h-part; plane n_ih over xg-part
        const short8* wnh = WnhHi + (size_t)g * 32 * 64 + lane;
        const short8* wnl = WnhLo + (size_t)g * 32 * 64 + lane;
        for (int kt = 0; kt < 32; kt++) {
            size_t o = (size_t)kt * 64;
            short8 A0H = a0h[o], A1H = a1h[o], A0L = a0l[o], A1L = a1l[o];
            short8 NH = wnh[o], NL = wnl[o];
            accA0 = __builtin_amdgcn_mfma_f32_16x16x32_bf16(A0H, NH, accA0, 0, 0, 0);
            accA1 = __builtin_amdgcn_mfma_f32_16x16x32_bf16(A1H, NH, accA1, 0, 0, 0);
            accA0 = __builtin_amdgcn_mfma_f32_16x16x32_bf16(A0H, NL, accA0, 0, 0, 0);
            accA1 = __builtin_amdgcn_mfma_f32_16x16x32_bf16(A1H, NL, accA1, 0, 0, 0);
            accA0 = __builtin_amdgcn_mfma_f32_16x16x32_bf16(A0L, NH, accA0, 0, 0, 0);
            accA1 = __builtin_amdgcn_mfma_f32_16x16x32_bf16(A1L, NH, accA1, 0, 0, 0);
        }
        const short8* wih = WniHi + (size_t)g * KTih * 64 + lane;
        const short8* wil = WniLo + (size_t)g * KTih * 64 + lane;
        for (int kt = 0; kt < KTih; kt++) {
            size_t o = (size_t)kt * 64;
            short8 A0H = b0h[o], A1H = b1h[o], A0L = b0l[o], A1L = b1l[o];
            short8 NH = wih[o], NL = wil[o];
            accB0 = __builtin_amdgcn_mfma_f32_16x16x32_bf16(A0H, NH, accB0, 0, 0, 0);
            accB1 = __builtin_amdgcn_mfma_f32_16x16x32_bf16(A1H, NH, accB1, 0, 0, 0);
            accB0 = __builtin_amdgcn_mfma_f32_16x16x32_bf16(A0H, NL, accB0, 0, 0, 0);
            accB1 = __builtin_amdgcn_mfma_f32_16x16x32_bf16(A1H, NL, accB1, 0, 0, 0);
            accB0 = __builtin_amdgcn_mfma_f32_16x16x32_bf16(A0L, NH, accB0, 0, 0, 0);
            accB1 = __builtin_amdgcn_mfma_f32_16x16x32_bf16(A1L, NH, accB1, 0, 0, 0);
        }
    }

    int rsub = (lane >> 4) * 4, cn = lane & 15;
    int p0 = nrole ? 2 : 0, p1 = nrole ? 3 : 1;
    int rb = mloc * 32;
#pragma unroll
    for (int r = 0; r < 4; r++) {
        sC[p0][rb + rsub + r][cn] = accA0[r];
        sC[p0][rb + 16 + rsub + r][cn] = accA1[r];
        sC[p1][rb + rsub + r][cn] = accB0[r];
        sC[p1][rb + 16 + rsub + r][cn] = accB1[r];
    }
    __syncthreads();

    if (tid < 128) {
        int m = tid & 63, oct = tid >> 6;
        int b = blockIdx.y * 64 + m;
        int gu0 = g * 16 + oct * 8;
        bool enc = (eaHi != nullptr);
        bool msk = enc ? (t < x_len[b]) : true;
        float ho[8], eo[8];
#pragma unroll
        for (int j = 0; j < 8; j++) {
            int ul = oct * 8 + j;
            int gu = g * 16 + ul;
            float rp = sC[0][m][ul] + bih[gu] + bhh[gu];
            float zp = sC[1][m][ul] + bih[UDIM + gu] + bhh[UDIM + gu];
            float hn = sC[2][m][ul] + bhh[2 * UDIM + gu];
            float inn = sC[3][m][ul] + bih[2 * UDIM + gu];
            float rg = sigm(rp), zg = sigm(zp);
            float nn = tanhf(inn + rg * hn);
            float hp = hinF[(size_t)b * UDIM + gu];
            float hv = (1.f - zg) * nn + zg * hp;
            ho[j] = msk ? hv : hp;
            eo[j] = msk ? hv : 0.f;
        }
#pragma unroll
        for (int j = 0; j < 8; j++) houtF[(size_t)b * UDIM + gu0 + j] = ho[j];
        writeSplit8(hoHi, hoLo, pkChunk(b, gu0, UDIM), ho);
        if (enc) writeSplit8(eaHi, eaLo, pkChunk(b * SLEN + t, gu0, UDIM), eo);
    }
}

// ---------------------------------------------------------------------------
// Attention scores + softmax + context + emb gather -> gx split-pack [B,1536]
// ---------------------------------------------------------------------------
__global__ __launch_bounds__(256) void attn_ctx(
    const float* __restrict__ encProj,
    const short* __restrict__ eaHi, const short* __restrict__ eaLo,
    const float* __restrict__ tmp2, const float* __restrict__ V_W,
    const float* __restrict__ V_b,
    const float* __restrict__ o2h_W, const float* __restrict__ o2h_b,
    const int* __restrict__ idx, short* __restrict__ gxHi, short* __restrict__ gxLo) {
    int b = blockIdx.x;
    int tid = threadIdx.x, lane = tid & 63, wave = tid >> 6;
    __shared__ float s_t2[UDIM];
    __shared__ float s_v[UDIM];
    __shared__ float s_attn[SLEN];
    for (int u = tid; u < UDIM; u += 256) {
        s_t2[u] = tmp2[(size_t)b * UDIM + u];
        s_v[u] = V_W[u];
    }
    __syncthreads();
    for (int s = wave; s < SLEN; s += 4) {
        const float4* ep4 = (const float4*)(encProj + ((size_t)b * SLEN + s) * UDIM);
        float p = 0.f;
        for (int u4 = lane; u4 < UDIM / 4; u4 += 64) {
            float4 e = ep4[u4];
            int u = 4 * u4;
            p += tanhf(e.x + s_t2[u]) * s_v[u] +
                 tanhf(e.y + s_t2[u + 1]) * s_v[u + 1] +
                 tanhf(e.z + s_t2[u + 2]) * s_v[u + 2] +
                 tanhf(e.w + s_t2[u + 3]) * s_v[u + 3];
        }
#pragma unroll
        for (int off = 32; off > 0; off >>= 1) p += __shfl_xor(p, off);
        if (lane == 0) s_attn[s] = p + V_b[0];
    }
    __syncthreads();
    if (tid < 64) {
        float v = s_attn[tid];
        float mx = v;
#pragma unroll
        for (int off = 32; off > 0; off >>= 1) mx = fmaxf(mx, __shfl_xor(mx, off));
        float e = expf(v - mx);
        float sum = e;
#pragma unroll
        for (int off = 32; off > 0; off >>= 1) sum += __shfl_xor(sum, off);
        s_attn[tid] = e / sum;
    }
    __syncthreads();
    if (tid < 128) {
        int u0 = tid * 8;
        float a[8] = {0, 0, 0, 0, 0, 0, 0, 0};
        const short8* hi8 = (const short8*)eaHi;
        const short8* lo8 = (const short8*)eaLo;
        int lanePart = 16 * ((u0 >> 3) & 3);
        int colPart = u0 >> 5;
        for (int s = 0; s < SLEN; s++) {
            int r = b * SLEN + s;
            size_t ch = ((size_t)(r >> 4) * (UDIM >> 5) + colPart) * 64 + (r & 15) + lanePart;
            S8 h, l;
            h.v = hi8[ch];
            l.v = lo8[ch];
            float w = s_attn[s];
#pragma unroll
            for (int j = 0; j < 8; j++) a[j] += w * (bf2f(h.s[j]) + bf2f(l.s[j]));
        }
        writeSplit8(gxHi, gxLo, pkChunk(b, u0, GXW), a);
    } else if (tid < 192) {
        int e0 = (tid - 128) * 8;
        int ib = idx[b];
        float a[8];
#pragma unroll
        for (int j = 0; j < 8; j++)
            a[j] = o2h_W[(size_t)(e0 + j) * VOUTD + ib] + o2h_b[e0 + j];
        writeSplit8(gxHi, gxLo, pkChunk(b, UDIM + e0, GXW), a);
    }
}

// ---------------------------------------------------------------------------
// Fused pred = h @ fc^T + fc_b, plus first-max argmax. Grid 4 (64 rows each).
// ---------------------------------------------------------------------------
__global__ __launch_bounds__(256) void fc_argmax(
    const short8* __restrict__ hHi, const short8* __restrict__ hLo,
    const short8* __restrict__ fcHi, const short8* __restrict__ fcLo,
    const float* __restrict__ fc_b, float* __restrict__ pred,
    int* __restrict__ idx) {
    __shared__ float sP[64][129];
    int tid = threadIdx.x, lane = tid & 63, wave = tid >> 6;
    int m16 = blockIdx.x * 4 + wave;
    const short8* ah = hHi + (size_t)m16 * 32 * 64 + lane;
    const short8* al = hLo + (size_t)m16 * 32 * 64 + lane;
    f32x4 acc[8] = {};
    for (int kt = 0; kt < 32; kt++) {
        size_t o = (size_t)kt * 64;
        short8 AH = ah[o], AL = al[o];
#pragma unroll
        for (int n = 0; n < 8; n++) {
            short8 WH = fcHi[((size_t)n * 32 + kt) * 64 + lane];
            short8 WL = fcLo[((size_t)n * 32 + kt) * 64 + lane];
            acc[n] = __builtin_amdgcn_mfma_f32_16x16x32_bf16(AH, WH, acc[n], 0, 0, 0);
            acc[n] = __builtin_amdgcn_mfma_f32_16x16x32_bf16(AH, WL, acc[n], 0, 0, 0);
            acc[n] = __builtin_amdgcn_mfma_f32_16x16x32_bf16(AL, WH, acc[n], 0, 0, 0);
        }
    }
    int rsub = (lane >> 4) * 4, cn = lane & 15;
#pragma unroll
    for (int n = 0; n < 8; n++) {
        float bb = fc_b[n * 16 + cn];
#pragma unroll
        for (int r = 0; r < 4; r++)
            sP[wave * 16 + rsub + r][n * 16 + cn] = acc[n][r] + bb;
    }
    __syncthreads();
    int b0 = blockIdx.x * 64;
    for (int i = tid; i < 64 * 128; i += 256)
        pred[(size_t)(b0 + (i >> 7)) * VOUTD + (i & 127)] = sP[i >> 7][i & 127];
    if (tid < 64) {
        float v = sP[tid][0];
        int bi = 0;
        for (int j = 1; j < 128; j++) {
            float w = sP[tid][j];
            if (w > v) { v = w; bi = j; }
        }
        idx[b0 + tid] = bi;
    }
}

// ---------------------------------------------------------------------------
extern "C" void kernel_launch(void* const* d_in, const int* in_sizes, int n_in,
                              void* d_out, int out_size, void* d_ws, size_t ws_size,
                              hipStream_t stream) {
    const float* x       = (const float*)d_in[0];
    const int*   x_len   = (const int*)d_in[1];
    const float* enc_Wih = (const float*)d_in[2];
    const float* enc_Whh = (const float*)d_in[3];
    const float* enc_bih = (const float*)d_in[4];
    const float* enc_bhh = (const float*)d_in[5];
    const float* dec_Wih = (const float*)d_in[6];
    const float* dec_Whh = (const float*)d_in[7];
    const float* dec_bih = (const float*)d_in[8];
    const float* dec_bhh = (const float*)d_in[9];
    const float* o2h_W   = (const float*)d_in[10];
    const float* o2h_b   = (const float*)d_in[11];
    const float* fc_W    = (const float*)d_in[12];
    const float* fc_b    = (const float*)d_in[13];
    const float* W1_W    = (const float*)d_in[14];
    const float* W1_b    = (const float*)d_in[15];
    const float* W2_W    = (const float*)d_in[16];
    const float* W2_b    = (const float*)d_in[17];
    const float* V_W     = (const float*)d_in[18];
    const float* V_b     = (const float*)d_in[19];
    float* out = (float*)d_out;

    char* p = (char*)d_ws;
    auto alloc = [&](size_t bytes) -> char* {
        char* q = p;
        p += (bytes + 255) & ~(size_t)255;
        return q;
    };
    // footprint ~195 MB (< round-5's proven 213 MB)
    float* hAF  = (float*)alloc((size_t)BATCH * UDIM * 4);
    float* hBF  = (float*)alloc((size_t)BATCH * UDIM * 4);
    short* hxAH = (short*)alloc((size_t)BATCH * UDIM * 2);
    short* hxAL = (short*)alloc((size_t)BATCH * UDIM * 2);
    short* hxBH = (short*)alloc((size_t)BATCH * UDIM * 2);
    short* hxBL = (short*)alloc((size_t)BATCH * UDIM * 2);
    float* tmp2 = (float*)alloc((size_t)BATCH * UDIM * 4);
    short* gxHi = (short*)alloc((size_t)BATCH * GXW * 2);
    short* gxLo = (short*)alloc((size_t)BATCH * GXW * 2);
    short* encAHi = (short*)alloc((size_t)BATCH * SLEN * UDIM * 2);
    short* encALo = (short*)alloc((size_t)BATCH * SLEN * UDIM * 2);
    float* encProjF = (float*)alloc((size_t)BATCH * SLEN * UDIM * 4);
    // enc weights: Wr/Wz K=1152; Wnh K=1024; Wni K=128
    short* eWrH = (short*)alloc((size_t)UDIM * 1152 * 2);
    short* eWrL = (short*)alloc((size_t)UDIM * 1152 * 2);
    short* eWzH = (short*)alloc((size_t)UDIM * 1152 * 2);
    short* eWzL = (short*)alloc((size_t)UDIM * 1152 * 2);
    short* eWnhH = (short*)alloc((size_t)UDIM * UDIM * 2);
    short* eWnhL = (short*)alloc((size_t)UDIM * UDIM * 2);
    short* eWniH = (short*)alloc((size_t)UDIM * VIND * 2);
    short* eWniL = (short*)alloc((size_t)UDIM * VIND * 2);
    // dec weights: Wr/Wz K=2560; Wnh K=1024; Wni K=1536
    short* dWrH = (short*)alloc((size_t)UDIM * 2560 * 2);
    short* dWrL = (short*)alloc((size_t)UDIM * 2560 * 2);
    short* dWzH = (short*)alloc((size_t)UDIM * 2560 * 2);
    short* dWzL = (short*)alloc((size_t)UDIM * 2560 * 2);
    short* dWnhH = (short*)alloc((size_t)UDIM * UDIM * 2);
    short* dWnhL = (short*)alloc((size_t)UDIM * UDIM * 2);
    short* dWniH = (short*)alloc((size_t)UDIM * GXW * 2);
    short* dWniL = (short*)alloc((size_t)UDIM * GXW * 2);
    short* w1Hi = (short*)alloc((size_t)UDIM * UDIM * 2);
    short* w1Lo = (short*)alloc((size_t)UDIM * UDIM * 2);
    short* w2Hi = (short*)alloc((size_t)UDIM * UDIM * 2);
    short* w2Lo = (short*)alloc((size_t)UDIM * UDIM * 2);
    short* fcHi = (short*)alloc((size_t)VOUTD * UDIM * 2);
    short* fcLo = (short*)alloc((size_t)VOUTD * UDIM * 2);
    short* xHi  = (short*)alloc((size_t)SLEN * BATCH * VIND * 2);
    short* xLo  = (short*)alloc((size_t)SLEN * BATCH * VIND * 2);
    int*   idx  = (int*)alloc(BATCH * 4);

    init_kernel<<<(BATCH * UDIM + 255) / 256, 256, 0, stream>>>(hAF, hxAH, hxAL, out, idx);

    auto packP = [&](const float* src, int rowOff, int K, short* Hi, short* Lo, int R) {
        int chunks = R * K / 8;
        pack_split2<<<(chunks + 255) / 256, 256, 0, stream>>>(src, rowOff, K, Hi, Lo, chunks);
    };
    auto packC = [&](const float* sA, int KA, int offA, const float* sB, int KB, int offB,
                     short* Hi, short* Lo, int R) {
        int chunks = R * (KA + KB) / 8;
        pack_cat<<<(chunks + 255) / 256, 256, 0, stream>>>(sA, KA, offA, sB, KB, offB, Hi, Lo, chunks);
    };
    packC(enc_Whh, UDIM, 0,        enc_Wih, VIND, 0,        eWrH, eWrL, UDIM);
    packC(enc_Whh, UDIM, UDIM,     enc_Wih, VIND, UDIM,     eWzH, eWzL, UDIM);
    packP(enc_Whh, 2 * UDIM, UDIM, eWnhH, eWnhL, UDIM);
    packP(enc_Wih, 2 * UDIM, VIND, eWniH, eWniL, UDIM);
    packC(dec_Whh, UDIM, 0,        dec_Wih, GXW, 0,         dWrH, dWrL, UDIM);
    packC(dec_Whh, UDIM, UDIM,     dec_Wih, GXW, UDIM,      dWzH, dWzL, UDIM);
    packP(dec_Whh, 2 * UDIM, UDIM, dWnhH, dWnhL, UDIM);
    packP(dec_Wih, 2 * UDIM, GXW,  dWniH, dWniL, UDIM);
    packP(W1_W, 0, UDIM, w1Hi, w1Lo, UDIM);
    packP(W2_W, 0, UDIM, w2Hi, w2Lo, UDIM);
    packP(fc_W, 0, UDIM, fcHi, fcLo, VOUTD);
    packP(x, 0, VIND, xHi, xLo, SLEN * BATCH);  // per-t block at offset t*256*128

    // ---- encoder: 64 fused steps ----
    float* hcF = hAF; float* hnF = hBF;
    short *hcH = hxAH, *hcL = hxAL, *hnH = hxBH, *hnL = hxBL;
    for (int t = 0; t < SLEN; t++) {
        const short8* xg = (const short8*)xHi + (size_t)t * (BATCH * VIND / 8);
        const short8* xl = (const short8*)xLo + (size_t)t * (BATCH * VIND / 8);
        gru_fused<<<dim3(64, 4), 256, 0, stream>>>(
            (const short8*)hcH, (const short8*)hcL, xg, xl,
            (const short8*)eWrH, (const short8*)eWrL,
            (const short8*)eWzH, (const short8*)eWzL,
            (const short8*)eWnhH, (const short8*)eWnhL,
            (const short8*)eWniH, (const short8*)eWniL,
            enc_bih, enc_bhh, hcF, hnF, hnH, hnL,
            encAHi, encALo, x_len, t, VIND / 32);
        { float* tf = hcF; hcF = hnF; hnF = tf; }
        { short* th = hcH; hcH = hnH; hnH = th; th = hcL; hcL = hnL; hnL = th; }
    }

    // ---- enc_proj = enc_out @ W1^T + W1_b (fp32, precision-critical) ----
    gemm_sp3<<<dim3(UDIM / 64, SLEN * BATCH / 64), 256, 0, stream>>>(
        (const short8*)encAHi, (const short8*)encALo,
        (const short8*)w1Hi, (const short8*)w1Lo,
        W1_b, encProjF, UDIM / 32, UDIM);

    // ---- greedy decode: 24 steps, 4 dispatches each ----
    for (int st = 0; st < TDEC - 1; st++) {
        gemm_sp3<<<dim3(UDIM / 64, BATCH / 64), 256, 0, stream>>>(
            (const short8*)hcH, (const short8*)hcL,
            (const short8*)w2Hi, (const short8*)w2Lo,
            W2_b, tmp2, UDIM / 32, UDIM);
        attn_ctx<<<BATCH, 256, 0, stream>>>(
            encProjF, encAHi, encALo, tmp2, V_W, V_b, o2h_W, o2h_b, idx, gxHi, gxLo);
        gru_fused<<<dim3(64, 4), 256, 0, stream>>>(
            (const short8*)hcH, (const short8*)hcL,
            (const short8*)gxHi, (const short8*)gxLo,
            (const short8*)dWrH, (const short8*)dWrL,
            (const short8*)dWzH, (const short8*)dWzL,
            (const short8*)dWnhH, (const short8*)dWnhL,
            (const short8*)dWniH, (const short8*)dWniL,
            dec_bih, dec_bhh, hcF, hnF, hnH, hnL,
            nullptr, nullptr, nullptr, 0, GXW / 32);
        float* pred = out + (size_t)(1 + st) * BATCH * VOUTD;
        fc_argmax<<<4, 256, 0, stream>>>(
            (const short8*)hnH, (const short8*)hnL,
            (const short8*)fcHi, (const short8*)fcLo,
            fc_b, pred, idx);
        { float* tf = hcF; hcF = hnF; hnF = tf; }
        { short* th = hcH; hcH = hnH; hnH = th; th = hcL; hcL = hnL; hnL = th; }
    }
}